// Round 3
// baseline (117.887 us; speedup 1.0000x reference)
//
#include <hip/hip_runtime.h>

// SlidingKernelAttention: unfold(k=4,s=1) -> per-(b,c,patch-offset) attention
// over seq=256 tokens of dim=16 -> overlap-add fold.
// B=2, C=64, H=W=67, Ho=Wo=64, N = B*C*16 = 2048 independent sequences.
//
// R12: DIAGNOSTIC ROUND. Four consecutive nulls (R8: -50 VALU/iter, R9 fat
// blocks, R10 launch_bounds+XCD+ILP, R11 half critical path + 2x waves) and
// pass1 has never appeared in the top-5 counter rows (the ~43-50us harness
// fills of the 268MB workspace outrank our ~36us kernel). This round
// triples the attention main loop (REP=3, accumulating into the SAME l and
// oacc; softmax normalization makes o*rcp(l) invariant under o->3o, l->3l,
// so output is unchanged to 1 rcp ulp) purely so pass1 lands in the top-5
// and we finally see MfmaUtil / VALUBusy / Occupancy / LDS_BANK_CONFLICT
// for the hot loop. An empty asm volatile "+v" on the Q-frags per rep
// blocks MFMA/exp2 CSE across reps (IntrNoMem otherwise collapses the
// reps). Loop body is bit-identical to R11 so counters describe R11's loop.
// Expect total ~125-145us this round; next round reverts REP=1 and applies
// the counter-indicated fix.
//
// MFMA layout identity (R5-R8): 16x16 MFMA C/D layout == A-operand layout
// == B-operand layout, so projection MFMA results ARE attention operands:
//   K^T = Wk.X^T    -> A-frag of K      (for S^T = K.Q^T)
//   V   = X.Wv^T    -> A-frag of V^T    (for O^T = V^T.P^T)
//   Q^T = s.Wq.X^T  -> B-frag of Q^T
//   P^T = exp2(S^T) -> B-frag of P^T    (in-register)
// All fragments statically indexed (R4 lesson: dynamic reg-array indexing
// -> scratch lowering). f16 vectors built via v_cvt_pkrtz + bit_cast /
// shufflevector only (R8: no sub-register insert/extract).

#define BATCH 2
#define CHAN 64
#define HWDIM 67
#define SEQ 256
#define DIM 16
#define NSEQ 2048            // BATCH*CHAN*16
#define PLANE 4096           // 64*64 elems per sequence
#define OUT_TOTAL (BATCH * CHAN * HWDIM * HWDIM)   // 574592
#define ATT_SCALE 0.70710678118654752f             // (DIM/HEADS)^-0.5
#define LOG2E 1.44269504088896340736f
#define HTILES 17            // ceil(67/4) output-row tiles per bc
#define REP 3                // diagnostic main-loop repetition (see header)

typedef _Float16 half4 __attribute__((ext_vector_type(4)));
typedef _Float16 half8 __attribute__((ext_vector_type(8)));
typedef float float4v __attribute__((ext_vector_type(4)));
typedef __fp16 fp16x2 __attribute__((ext_vector_type(2)));
typedef unsigned int uint2v __attribute__((ext_vector_type(2)));

// 2x v_cvt_pkrtz + register-pair aliasing: zero insert/extract VALU.
static __device__ __forceinline__ half4 mk_half4(float a, float b, float c, float d) {
    fp16x2 lo = __builtin_amdgcn_cvt_pkrtz(a, b);
    fp16x2 hi = __builtin_amdgcn_cvt_pkrtz(c, d);
    uint2v u;
    u[0] = __builtin_bit_cast(unsigned int, lo);
    u[1] = __builtin_bit_cast(unsigned int, hi);
    return __builtin_bit_cast(half4, u);
}

static __device__ __forceinline__ half4 pack4(float4v c) {
    return mk_half4(c[0], c[1], c[2], c[3]);
}

// one q-tile step: exp2 the 4 scores, accumulate denominator, pack,
// accumulate O^T.
static __device__ __forceinline__ void att_step(const half4 vf, const float4v sfr,
                                                float& l, float4v& oacc) {
    const float p0 = __builtin_amdgcn_exp2f(sfr[0]);
    const float p1 = __builtin_amdgcn_exp2f(sfr[1]);
    const float p2 = __builtin_amdgcn_exp2f(sfr[2]);
    const float p3 = __builtin_amdgcn_exp2f(sfr[3]);
    l += (p0 + p1) + (p2 + p3);
    const half4 pb = mk_half4(p0, p1, p2, p3);
    oacc = __builtin_amdgcn_mfma_f32_16x16x16f16(vf, pb, oacc, 0, 0, 0);
}

__global__ __launch_bounds__(512, 6) void ska_attn_pass1(
    const float* __restrict__ x,      // [B, C, 67, 67]
    const float* __restrict__ w,      // [48, 16]
    _Float16* __restrict__ ao)        // [NSEQ, 64, 64] workspace (f16)
{
    // one sequence per block. buf[t][0:4] holds the X-frag until tile t's
    // projection, then [0:4]=K A-frag | [4:8]=V^T A-frag. 16 KB.
    __shared__ __align__(16) _Float16 buf[16][64][8];

    // XCD chunked swizzle: 2048 blocks = 8 XCDs x 256 -> 16 whole bc's per
    // XCD; x-plane and ao for a bc live in exactly one XCD's L2.
    const int n = (int)(blockIdx.x & 7) * 256 + (int)(blockIdx.x >> 3);

    const int p  = n & 15;
    const int bc = n >> 4;
    const int oi = p >> 2;
    const int oj = p & 3;

    const int tid = threadIdx.x;
    const int s   = tid >> 1;             // token id 0..255
    const int ph  = s >> 2;
    const int pw0 = (s & 3) * DIM;
    const int dh2 = (tid & 1) * 2;        // this thread stages feature
                                          // groups dh2, dh2+1 (8 floats)

    // stage: 2 threads per token, 8 features each, as f16 X-fragment rows.
    // wave w covers tid 64w..64w+63 == tokens 32w..32w+31 == tiles 2w,2w+1.
    const float* xrow = x + ((size_t)bc * HWDIM + (ph + oi)) * HWDIM + pw0 + oj;
    const int kt = s >> 4, kk = s & 15;
#pragma unroll
    for (int dd = 0; dd < 2; ++dd) {
        const int dh = dh2 + dd;
        const half4 h = mk_half4(xrow[4 * dh + 0], xrow[4 * dh + 1],
                                 xrow[4 * dh + 2], xrow[4 * dh + 3]);
        *(half4*)&buf[kt][kk + 16 * dh][0] = h;
    }

    const int wave = tid >> 6;    // 0..7: owns q/k tiles 2w, 2w+1
    const int lane = tid & 63;
    const int o = lane & 15;      // weight output row held by this lane
    const int g = lane >> 4;      // k-group

    // weight fragments straight from global (3 KB, L1-resident)
    const float4 wq4 = *(const float4*)(w + ( 0 + o) * DIM + 4 * g);
    const float4 wk4 = *(const float4*)(w + (16 + o) * DIM + 4 * g);
    const float4 wv4 = *(const float4*)(w + (32 + o) * DIM + 4 * g);
    const half4 wqf = mk_half4(wq4.x * (ATT_SCALE * LOG2E), wq4.y * (ATT_SCALE * LOG2E),
                               wq4.z * (ATT_SCALE * LOG2E), wq4.w * (ATT_SCALE * LOG2E));
    const half4 wkf = mk_half4(wk4.x, wk4.y, wk4.z, wk4.w);
    const half4 wvf = mk_half4(wv4.x, wv4.y, wv4.z, wv4.w);

    const float4v zf = (float4v){0.f, 0.f, 0.f, 0.f};

    // projection: wave w handles tiles 2w, 2w+1 (the tiles it staged — no
    // barrier needed; xF portion of buf[t] is dead after kv write of tile t).
    half4 qfr[2];
#pragma unroll
    for (int u = 0; u < 2; ++u) {
        const int t = 2 * wave + u;
        const half4 xf = *(const half4*)&buf[t][lane][0];
        const half4 kf = pack4(__builtin_amdgcn_mfma_f32_16x16x16f16(wkf, xf, zf, 0, 0, 0));
        const half4 vf = pack4(__builtin_amdgcn_mfma_f32_16x16x16f16(xf, wvf, zf, 0, 0, 0));
        const half8 kv = __builtin_shufflevector(kf, vf, 0, 1, 2, 3, 4, 5, 6, 7);
        *(half8*)&buf[t][lane][0] = kv;
        qfr[u] = pack4(__builtin_amdgcn_mfma_f32_16x16x16f16(wqf, xf, zf, 0, 0, 0));
    }
    __syncthreads();   // kv frags ready (the only barrier)

    float4v oacc0 = zf, oacc1 = zf;
    float l0 = 0.f, l1 = 0.f;

    // DIAGNOSTIC: run the identical main loop REP times, accumulating into
    // the same l/oacc. The asm makes qfr opaque each rep so the MFMA/exp2
    // chains can't be CSE'd; softmax cancels the 3x in o and l exactly.
    for (int rep = 0; rep < REP; ++rep) {
        asm volatile("" : "+v"(qfr[0]), "+v"(qfr[1]));
        half8 kvc = *(const half8*)&buf[0][lane][0];
#pragma unroll 4
        for (int t = 0; t < 16; ++t) {
            const half8 kvn = *(const half8*)&buf[(t + 1) & 15][lane][0];
            const half4 kf = __builtin_shufflevector(kvc, kvc, 0, 1, 2, 3);
            const half4 vf = __builtin_shufflevector(kvc, kvc, 4, 5, 6, 7);
            const float4v s0 = __builtin_amdgcn_mfma_f32_16x16x16f16(kf, qfr[0], zf, 0, 0, 0);
            const float4v s1 = __builtin_amdgcn_mfma_f32_16x16x16f16(kf, qfr[1], zf, 0, 0, 0);
            att_step(vf, s0, l0, oacc0);
            att_step(vf, s1, l1, oacc1);
            kvc = kvn;
        }
    }

    // softmax denom: sum lane groups {qq, qq+16, qq+32, qq+48}; store O^T frag
#pragma unroll
    for (int j = 0; j < 2; ++j) {
        float lj = j ? l1 : l0;
        lj += __shfl_xor(lj, 16, 64);
        lj += __shfl_xor(lj, 32, 64);
        const float rl = __builtin_amdgcn_rcpf(lj);
        const float4v oa = j ? oacc1 : oacc0;
        const int query = (2 * wave + j) * 16 + o;
        const half4 hv = mk_half4(oa[0] * rl, oa[1] * rl,
                                  oa[2] * rl, oa[3] * rl);
        *(half4*)(ao + (size_t)n * PLANE + query * DIM + 4 * g) = hv;
    }
}

// pass 2: block = (bc, 4 output rows). Stage the 16 planes x 4 rows of ao
// this block needs (8 KB) with coalesced 16B loads, then each pixel sums 16
// LDS halves. sA[pl][hh] holds ao[bc*16+pl][h0+hh - (pl>>2)][0:64] (0 if OOB).
__global__ __launch_bounds__(256) void ska_fold_pass2(
    const _Float16* __restrict__ ao,  // [NSEQ, 64, 64] f16
    float* __restrict__ out)          // [B, C, 67, 67]
{
    __shared__ __align__(16) _Float16 sA[16][4][64];   // 8 KB

    // XCD chunked swizzle: 2176 blocks = 8 XCDs x 272 = 8 x (16 bc x 17
    // tiles). XCD k folds bc [16k,16k+16) — exactly the bc's whose ao was
    // written by pass1 on XCD k, so the staging reads hit warm L2.
    const int blk = (int)(blockIdx.x & 7) * 272 + (int)(blockIdx.x >> 3);
    const int h0  = (blk % HTILES) * 4;
    const int bc  = blk / HTILES;
    const int tid = threadIdx.x;

    // stage: 4096 halves, 16 per thread as 2x half8
    {
        const int pl = tid >> 4;           // plane 0..15
        const int hh = (tid >> 2) & 3;     // local row 0..3
        const int pw = (tid & 3) * 16;     // col base 0/16/32/48
        const int i  = pl >> 2;
        const int prow = h0 + hh - i;      // source plane row
        half8 v0, v1;
        if (prow >= 0 && prow < 64) {
            const _Float16* src = ao + ((size_t)(bc * 16 + pl)) * PLANE + prow * 64 + pw;
            v0 = *(const half8*)src;
            v1 = *(const half8*)(src + 8);
        } else {
            const half8 z = (half8)(_Float16)0.f;
            v0 = z; v1 = z;
        }
        *(half8*)&sA[pl][hh][pw]     = v0;
        *(half8*)&sA[pl][hh][pw + 8] = v1;
    }
    __syncthreads();

    for (int px = tid; px < 4 * HWDIM; px += 256) {
        const int hh = px / HWDIM;
        const int ww = px % HWDIM;
        const int h  = h0 + hh;
        if (h >= HWDIM) continue;
        float acc = 0.f;
#pragma unroll
        for (int i = 0; i < 4; ++i) {
#pragma unroll
            for (int j = 0; j < 4; ++j) {
                const int pw = ww - j;
                if (pw < 0 || pw >= 64) continue;
                acc += (float)sA[i * 4 + j][hh][pw];
            }
        }
        out[((size_t)bc * HWDIM + h) * HWDIM + ww] = acc;
    }
}

// ---- fallback (atomic fold) if workspace is too small ----
__global__ __launch_bounds__(256) void ska_attn_atomic(
    const float* __restrict__ x, const float* __restrict__ w,
    float* __restrict__ out)
{
    __shared__ float sw[3 * DIM * DIM];
    __shared__ float sk[SEQ][DIM];
    __shared__ float sv[SEQ][DIM];

    const int n = blockIdx.x, p = n & 15, bc = n >> 4, oi = p >> 2, oj = p & 3;
    const int s = threadIdx.x, ph = s >> 2, pw0 = (s & 3) * DIM;

#pragma unroll
    for (int r = 0; r < 3; ++r) sw[r * 256 + s] = w[r * 256 + s];

    const float* xrow = x + ((size_t)bc * HWDIM + (ph + oi)) * HWDIM + pw0 + oj;
    float xr[DIM];
#pragma unroll
    for (int d = 0; d < DIM; ++d) xr[d] = xrow[d];
    __syncthreads();

    float q[DIM];
#pragma unroll
    for (int o = 0; o < DIM; ++o) {
        float aq = 0.f, ak = 0.f, av = 0.f;
#pragma unroll
        for (int d = 0; d < DIM; ++d) {
            aq += xr[d] * sw[o * DIM + d];
            ak += xr[d] * sw[(DIM + o) * DIM + d];
            av += xr[d] * sw[(2 * DIM + o) * DIM + d];
        }
        q[o] = aq * ATT_SCALE; sk[s][o] = ak; sv[s][o] = av;
    }
    __syncthreads();

    float l = 0.f, acc[DIM];
#pragma unroll
    for (int d = 0; d < DIM; ++d) acc[d] = 0.f;
    for (int t = 0; t < SEQ; ++t) {
        float sc = 0.f;
#pragma unroll
        for (int d = 0; d < DIM; ++d) sc += q[d] * sk[t][d];
        const float pe = __expf(sc);
        l += pe;
#pragma unroll
        for (int d = 0; d < DIM; ++d) acc[d] += pe * sv[t][d];
    }
    const float rl = 1.f / l;
    float* obase = out + ((size_t)bc * HWDIM + (ph + oi)) * HWDIM + pw0 + oj;
#pragma unroll
    for (int d = 0; d < DIM; ++d) atomicAdd(&obase[d], acc[d] * rl);
}

extern "C" void kernel_launch(void* const* d_in, const int* in_sizes, int n_in,
                              void* d_out, int out_size, void* d_ws, size_t ws_size,
                              hipStream_t stream) {
    const float* x = (const float*)d_in[0];
    const float* w = (const float*)d_in[1];
    float* out = (float*)d_out;

    const size_t need = (size_t)NSEQ * PLANE * sizeof(_Float16);   // 16.8 MB
    if (ws_size >= need) {
        _Float16* ao = (_Float16*)d_ws;
        ska_attn_pass1<<<NSEQ, 512, 0, stream>>>(x, w, ao);
        ska_fold_pass2<<<BATCH * CHAN * HTILES, 256, 0, stream>>>(ao, out);
    } else {
        (void)hipMemsetAsync(out, 0, (size_t)out_size * sizeof(float), stream);
        ska_attn_atomic<<<NSEQ, 256, 0, stream>>>(x, w, out);
    }
}

// Round 4
// 88.886 us; speedup vs baseline: 1.3263x; 1.3263x over previous
//
#include <hip/hip_runtime.h>

// SlidingKernelAttention: unfold(k=4,s=1) -> per-(b,c,patch-offset) attention
// over seq=256 tokens of dim=16 -> overlap-add fold.
// B=2, C=64, H=W=67, Ho=Wo=64, N = B*C*16 = 2048 independent sequences.
//
// R13 = R11 with the X staging round-trip eliminated. R12's REP=3 diagnostic
// decomposed pass1 (36us) into main loop M=11us (trans/VALU-issue-bound at
// ~floor: 134M chip-wide exp2 ~ 7us irreducible; VALUBusy accounting closes
// at 70%) + REP-independent P=25us (VALUBusy ~40%: staging chain, LDS
// round-trip, projection, epilogue, ramp). This round cuts P: the
// projection's X B-fragment is "lane holds features 4g..4g+3 of token
// o=lane&15 of tile t", so each lane loads those 4 floats DIRECTLY from
// global into the fragment. Deletes the 512-thread staging loop (8 scalar
// loads + 4 cvt + 2 ds_write per thread), the projection ds_read, and the
// ~300-cycle lgkm-chained LDS round trip. Same total x bytes (each tile
// still loaded once per block). KV frags still stage through LDS; one
// barrier survives. Main loop & epilogue identical to R11 (M is at floor).
//
// MFMA layout identity (R5-R8): 16x16 MFMA C/D layout == A-operand layout
// == B-operand layout, so projection MFMA results ARE attention operands:
//   K^T = Wk.X^T    -> A-frag of K      (for S^T = K.Q^T)
//   V   = X.Wv^T    -> A-frag of V^T    (for O^T = V^T.P^T)
//   Q^T = s.Wq.X^T  -> B-frag of Q^T
//   P^T = exp2(S^T) -> B-frag of P^T    (in-register)
// All fragments statically indexed (R4 lesson: dynamic reg-array indexing
// -> scratch lowering). f16 vectors built via v_cvt_pkrtz + bit_cast /
// shufflevector only (R8: no sub-register insert/extract).
// Timed window includes a ~43-50us harness fill of the 268MB d_ws
// (read deltas as total minus the per-run fill dur from the counters).

#define BATCH 2
#define CHAN 64
#define HWDIM 67
#define SEQ 256
#define DIM 16
#define NSEQ 2048            // BATCH*CHAN*16
#define PLANE 4096           // 64*64 elems per sequence
#define OUT_TOTAL (BATCH * CHAN * HWDIM * HWDIM)   // 574592
#define ATT_SCALE 0.70710678118654752f             // (DIM/HEADS)^-0.5
#define LOG2E 1.44269504088896340736f
#define HTILES 17            // ceil(67/4) output-row tiles per bc

typedef _Float16 half4 __attribute__((ext_vector_type(4)));
typedef _Float16 half8 __attribute__((ext_vector_type(8)));
typedef float float4v __attribute__((ext_vector_type(4)));
typedef __fp16 fp16x2 __attribute__((ext_vector_type(2)));
typedef unsigned int uint2v __attribute__((ext_vector_type(2)));

// 2x v_cvt_pkrtz + register-pair aliasing: zero insert/extract VALU.
static __device__ __forceinline__ half4 mk_half4(float a, float b, float c, float d) {
    fp16x2 lo = __builtin_amdgcn_cvt_pkrtz(a, b);
    fp16x2 hi = __builtin_amdgcn_cvt_pkrtz(c, d);
    uint2v u;
    u[0] = __builtin_bit_cast(unsigned int, lo);
    u[1] = __builtin_bit_cast(unsigned int, hi);
    return __builtin_bit_cast(half4, u);
}

static __device__ __forceinline__ half4 pack4(float4v c) {
    return mk_half4(c[0], c[1], c[2], c[3]);
}

// one q-tile step: exp2 the 4 scores, accumulate denominator, pack,
// accumulate O^T.
static __device__ __forceinline__ void att_step(const half4 vf, const float4v sfr,
                                                float& l, float4v& oacc) {
    const float p0 = __builtin_amdgcn_exp2f(sfr[0]);
    const float p1 = __builtin_amdgcn_exp2f(sfr[1]);
    const float p2 = __builtin_amdgcn_exp2f(sfr[2]);
    const float p3 = __builtin_amdgcn_exp2f(sfr[3]);
    l += (p0 + p1) + (p2 + p3);
    const half4 pb = mk_half4(p0, p1, p2, p3);
    oacc = __builtin_amdgcn_mfma_f32_16x16x16f16(vf, pb, oacc, 0, 0, 0);
}

__global__ __launch_bounds__(512, 6) void ska_attn_pass1(
    const float* __restrict__ x,      // [B, C, 67, 67]
    const float* __restrict__ w,      // [48, 16]
    _Float16* __restrict__ ao)        // [NSEQ, 64, 64] workspace (f16)
{
    // one sequence per block. buf[t] holds tile t's KV fragments:
    // [0:4]=K A-frag | [4:8]=V^T A-frag. 16 KB.
    __shared__ __align__(16) _Float16 buf[16][64][8];

    // XCD chunked swizzle: 2048 blocks = 8 XCDs x 256 -> 16 whole bc's per
    // XCD; x-plane and ao for a bc live in exactly one XCD's L2.
    const int n = (int)(blockIdx.x & 7) * 256 + (int)(blockIdx.x >> 3);

    const int p  = n & 15;
    const int bc = n >> 4;
    const int oi = p >> 2;
    const int oj = p & 3;

    const int tid  = threadIdx.x;
    const int wave = tid >> 6;    // 0..7: owns q/k tiles 2w, 2w+1
    const int lane = tid & 63;
    const int o = lane & 15;      // token (and weight output row) for this lane
    const int g = lane >> 4;      // feature group (k-group)

    // weight fragments straight from global (3 KB, L1-resident)
    const float4 wq4 = *(const float4*)(w + ( 0 + o) * DIM + 4 * g);
    const float4 wk4 = *(const float4*)(w + (16 + o) * DIM + 4 * g);
    const float4 wv4 = *(const float4*)(w + (32 + o) * DIM + 4 * g);
    const half4 wqf = mk_half4(wq4.x * (ATT_SCALE * LOG2E), wq4.y * (ATT_SCALE * LOG2E),
                               wq4.z * (ATT_SCALE * LOG2E), wq4.w * (ATT_SCALE * LOG2E));
    const half4 wkf = mk_half4(wk4.x, wk4.y, wk4.z, wk4.w);
    const half4 wvf = mk_half4(wv4.x, wv4.y, wv4.z, wv4.w);

    const float4v zf = (float4v){0.f, 0.f, 0.f, 0.f};

    // projection, X direct-to-register: lane (o,g) of tile t holds features
    // 4g..4g+3 of token s = t*16+o, i.e. x[bc][oi + 4t + (o>>2)][oj +
    // (o&3)*16 + 4g .. +3]. One 4-float load straight into the B-frag; no
    // X staging, no LDS round trip. Wave w owns tiles 2w, 2w+1.
    const int rowbase = bc * (HWDIM * HWDIM) + oi * HWDIM + oj;
    const int col = (o & 3) * 16 + 4 * g;
    half4 qfr[2];
#pragma unroll
    for (int u = 0; u < 2; ++u) {
        const int t = 2 * wave + u;
        const float* xp = x + rowbase + (4 * t + (o >> 2)) * HWDIM + col;
        const half4 xf = mk_half4(xp[0], xp[1], xp[2], xp[3]);
        const half4 kf = pack4(__builtin_amdgcn_mfma_f32_16x16x16f16(wkf, xf, zf, 0, 0, 0));
        const half4 vf = pack4(__builtin_amdgcn_mfma_f32_16x16x16f16(xf, wvf, zf, 0, 0, 0));
        const half8 kv = __builtin_shufflevector(kf, vf, 0, 1, 2, 3, 4, 5, 6, 7);
        *(half8*)&buf[t][lane][0] = kv;
        qfr[u] = pack4(__builtin_amdgcn_mfma_f32_16x16x16f16(wqf, xf, zf, 0, 0, 0));
    }
    __syncthreads();   // kv frags ready (the only barrier)

    float4v oacc0 = zf, oacc1 = zf;
    float l0 = 0.f, l1 = 0.f;

    // main loop: one ds_read_b128 per k-tile, prefetched one tile ahead;
    // the 2 S-MFMAs (independent q-tiles) issue before the exp2/pack/O-MFMA
    // phase so MFMA latency overlaps VALU work. (Unchanged from R11 — R12
    // showed this loop is trans/VALU-issue-bound at ~its floor.)
    half8 kvc = *(const half8*)&buf[0][lane][0];
#pragma unroll 4
    for (int t = 0; t < 16; ++t) {
        const half8 kvn = *(const half8*)&buf[(t + 1) & 15][lane][0];
        const half4 kf = __builtin_shufflevector(kvc, kvc, 0, 1, 2, 3);
        const half4 vf = __builtin_shufflevector(kvc, kvc, 4, 5, 6, 7);
        const float4v s0 = __builtin_amdgcn_mfma_f32_16x16x16f16(kf, qfr[0], zf, 0, 0, 0);
        const float4v s1 = __builtin_amdgcn_mfma_f32_16x16x16f16(kf, qfr[1], zf, 0, 0, 0);
        att_step(vf, s0, l0, oacc0);
        att_step(vf, s1, l1, oacc1);
        kvc = kvn;
    }

    // softmax denom: sum lane groups {qq, qq+16, qq+32, qq+48}; store O^T frag
#pragma unroll
    for (int j = 0; j < 2; ++j) {
        float lj = j ? l1 : l0;
        lj += __shfl_xor(lj, 16, 64);
        lj += __shfl_xor(lj, 32, 64);
        const float rl = __builtin_amdgcn_rcpf(lj);
        const float4v oa = j ? oacc1 : oacc0;
        const int query = (2 * wave + j) * 16 + o;
        const half4 hv = mk_half4(oa[0] * rl, oa[1] * rl,
                                  oa[2] * rl, oa[3] * rl);
        *(half4*)(ao + (size_t)n * PLANE + query * DIM + 4 * g) = hv;
    }
}

// pass 2: block = (bc, 4 output rows). Stage the 16 planes x 4 rows of ao
// this block needs (8 KB) with coalesced 16B loads, then each pixel sums 16
// LDS halves. sA[pl][hh] holds ao[bc*16+pl][h0+hh - (pl>>2)][0:64] (0 if OOB).
__global__ __launch_bounds__(256) void ska_fold_pass2(
    const _Float16* __restrict__ ao,  // [NSEQ, 64, 64] f16
    float* __restrict__ out)          // [B, C, 67, 67]
{
    __shared__ __align__(16) _Float16 sA[16][4][64];   // 8 KB

    // XCD chunked swizzle: 2176 blocks = 8 XCDs x 272 = 8 x (16 bc x 17
    // tiles). XCD k folds bc [16k,16k+16) — exactly the bc's whose ao was
    // written by pass1 on XCD k, so the staging reads hit warm L2.
    const int blk = (int)(blockIdx.x & 7) * 272 + (int)(blockIdx.x >> 3);
    const int h0  = (blk % HTILES) * 4;
    const int bc  = blk / HTILES;
    const int tid = threadIdx.x;

    // stage: 4096 halves, 16 per thread as 2x half8
    {
        const int pl = tid >> 4;           // plane 0..15
        const int hh = (tid >> 2) & 3;     // local row 0..3
        const int pw = (tid & 3) * 16;     // col base 0/16/32/48
        const int i  = pl >> 2;
        const int prow = h0 + hh - i;      // source plane row
        half8 v0, v1;
        if (prow >= 0 && prow < 64) {
            const _Float16* src = ao + ((size_t)(bc * 16 + pl)) * PLANE + prow * 64 + pw;
            v0 = *(const half8*)src;
            v1 = *(const half8*)(src + 8);
        } else {
            const half8 z = (half8)(_Float16)0.f;
            v0 = z; v1 = z;
        }
        *(half8*)&sA[pl][hh][pw]     = v0;
        *(half8*)&sA[pl][hh][pw + 8] = v1;
    }
    __syncthreads();

    for (int px = tid; px < 4 * HWDIM; px += 256) {
        const int hh = px / HWDIM;
        const int ww = px % HWDIM;
        const int h  = h0 + hh;
        if (h >= HWDIM) continue;
        float acc = 0.f;
#pragma unroll
        for (int i = 0; i < 4; ++i) {
#pragma unroll
            for (int j = 0; j < 4; ++j) {
                const int pw = ww - j;
                if (pw < 0 || pw >= 64) continue;
                acc += (float)sA[i * 4 + j][hh][pw];
            }
        }
        out[((size_t)bc * HWDIM + h) * HWDIM + ww] = acc;
    }
}

// ---- fallback (atomic fold) if workspace is too small ----
__global__ __launch_bounds__(256) void ska_attn_atomic(
    const float* __restrict__ x, const float* __restrict__ w,
    float* __restrict__ out)
{
    __shared__ float sw[3 * DIM * DIM];
    __shared__ float sk[SEQ][DIM];
    __shared__ float sv[SEQ][DIM];

    const int n = blockIdx.x, p = n & 15, bc = n >> 4, oi = p >> 2, oj = p & 3;
    const int s = threadIdx.x, ph = s >> 2, pw0 = (s & 3) * DIM;

#pragma unroll
    for (int r = 0; r < 3; ++r) sw[r * 256 + s] = w[r * 256 + s];

    const float* xrow = x + ((size_t)bc * HWDIM + (ph + oi)) * HWDIM + pw0 + oj;
    float xr[DIM];
#pragma unroll
    for (int d = 0; d < DIM; ++d) xr[d] = xrow[d];
    __syncthreads();

    float q[DIM];
#pragma unroll
    for (int o = 0; o < DIM; ++o) {
        float aq = 0.f, ak = 0.f, av = 0.f;
#pragma unroll
        for (int d = 0; d < DIM; ++d) {
            aq += xr[d] * sw[o * DIM + d];
            ak += xr[d] * sw[(DIM + o) * DIM + d];
            av += xr[d] * sw[(2 * DIM + o) * DIM + d];
        }
        q[o] = aq * ATT_SCALE; sk[s][o] = ak; sv[s][o] = av;
    }
    __syncthreads();

    float l = 0.f, acc[DIM];
#pragma unroll
    for (int d = 0; d < DIM; ++d) acc[d] = 0.f;
    for (int t = 0; t < SEQ; ++t) {
        float sc = 0.f;
#pragma unroll
        for (int d = 0; d < DIM; ++d) sc += q[d] * sk[t][d];
        const float pe = __expf(sc);
        l += pe;
#pragma unroll
        for (int d = 0; d < DIM; ++d) acc[d] += pe * sv[t][d];
    }
    const float rl = 1.f / l;
    float* obase = out + ((size_t)bc * HWDIM + (ph + oi)) * HWDIM + pw0 + oj;
#pragma unroll
    for (int d = 0; d < DIM; ++d) atomicAdd(&obase[d], acc[d] * rl);
}

extern "C" void kernel_launch(void* const* d_in, const int* in_sizes, int n_in,
                              void* d_out, int out_size, void* d_ws, size_t ws_size,
                              hipStream_t stream) {
    const float* x = (const float*)d_in[0];
    const float* w = (const float*)d_in[1];
    float* out = (float*)d_out;

    const size_t need = (size_t)NSEQ * PLANE * sizeof(_Float16);   // 16.8 MB
    if (ws_size >= need) {
        _Float16* ao = (_Float16*)d_ws;
        ska_attn_pass1<<<NSEQ, 512, 0, stream>>>(x, w, ao);
        ska_fold_pass2<<<BATCH * CHAN * HTILES, 256, 0, stream>>>(ao, out);
    } else {
        (void)hipMemsetAsync(out, 0, (size_t)out_size * sizeof(float), stream);
        ska_attn_atomic<<<NSEQ, 256, 0, stream>>>(x, w, out);
    }
}